// Round 5
// baseline (13008.951 us; speedup 1.0000x reference)
//
#include <hip/hip_runtime.h>
#include <hip/hip_bf16.h>

// Problem dims
#define B_   512
#define WIN_ 128
#define D_   256
#define H_   512
#define O_   64
#define P_   64
#define K2H  1024   // 2H (q = [h|c])
#define NQY  320    // packed Wq(256 rows) + Wd(64 rows, K-padded) weights
#define NG   2048   // 4*H gate dims

typedef __attribute__((ext_vector_type(8))) short bf16x8;
typedef __attribute__((ext_vector_type(4))) float f32x4;
using bf16 = __hip_bfloat16;

__device__ __forceinline__ float fast_tanh(float x){
    float e = __expf(2.f * x);
    return 1.f - __fdividef(2.f, e + 1.f);
}
__device__ __forceinline__ float fast_sig(float x){
    return __fdividef(1.f, 1.f + __expf(-x));
}
__device__ __forceinline__ float b_lo(unsigned int u){ return __uint_as_float(u << 16); }
__device__ __forceinline__ float b_hi(unsigned int u){ return __uint_as_float(u & 0xffff0000u); }
__device__ __forceinline__ short f2bs(float v){
    return (short)__builtin_bit_cast(unsigned short, __float2bfloat16(v));
}
__device__ __forceinline__ unsigned int pack2(float a, float b){
    unsigned short sa = __builtin_bit_cast(unsigned short, __float2bfloat16(a));
    unsigned short sb = __builtin_bit_cast(unsigned short, __float2bfloat16(b));
    return (unsigned int)sa | ((unsigned int)sb << 16);
}

// ---------------- prep: dtype conversions + weight packing ----------------
__global__ void k_prep(const float* __restrict__ x, const float* __restrict__ W,
                       const float* __restrict__ U, const float* __restrict__ W_ih,
                       const float* __restrict__ W_hh, const float* __restrict__ b_ih,
                       const float* __restrict__ b_hh, const float* __restrict__ Wd,
                       const float* __restrict__ Ws, const float* __restrict__ Wc,
                       bf16* __restrict__ x_bf, bf16* __restrict__ Wqy,
                       bf16* __restrict__ Wctx, bf16* __restrict__ Whh_bf,
                       bf16* __restrict__ U_bf, bf16* __restrict__ Wsc,
                       float* __restrict__ bsum)
{
    const long NXv = (long)B_ * WIN_ * D_ / 8;    // 2,097,152 (8 floats each)
    const long NCTX= (long)NG * D_;               // 524,288
    const long NWQ = (long)NQY * K2H;             // 327,680
    const long NU  = (long)D_ * D_;               // 65,536
    const long NHH = (long)NG * H_;               // 1,048,576
    const long NWS = (long)K2H * D_;              // 262,144
    const long NB  = NG;
    const long total = NXv + NCTX + NWQ + NU + NHH + NWS + NB;
    for (long i = (long)blockIdx.x * blockDim.x + threadIdx.x; i < total;
         i += (long)gridDim.x * blockDim.x) {
        long j = i;
        if (j < NXv) {
            const float4* xp = (const float4*)x + j * 2;
            float4 a = xp[0], b = xp[1];
            bf16x8 v;
            v[0] = f2bs(a.x); v[1] = f2bs(a.y); v[2] = f2bs(a.z); v[3] = f2bs(a.w);
            v[4] = f2bs(b.x); v[5] = f2bs(b.y); v[6] = f2bs(b.z); v[7] = f2bs(b.w);
            *(bf16x8*)((short*)x_bf + j * 8) = v;
            continue;
        }
        j -= NXv;
        if (j < NCTX) {     // Wctx[gj][d] = W_ih[gj][64+d]
            long gj = j / D_, d = j % D_;
            Wctx[j] = __float2bfloat16(W_ih[gj * 320 + 64 + d]); continue;
        }
        j -= NCTX;
        if (j < NWQ) {      // [W ; Wd(K-padded)]
            long n = j / K2H, k = j % K2H;
            float v;
            if (n < 256) v = W[n * K2H + k];
            else { long o = n - 256; v = (k < 512) ? Wd[o * 512 + k] : 0.f; }
            Wqy[j] = __float2bfloat16(v); continue;
        }
        j -= NWQ;
        if (j < NU) { U_bf[j] = __float2bfloat16(U[j]); continue; }
        j -= NU;
        if (j < NHH) { Whh_bf[j] = __float2bfloat16(W_hh[j]); continue; }
        j -= NHH;
        if (j < NWS) {      // [Ws;Wc]
            long n = j / D_, k = j % D_;
            float v = (n < 512) ? Ws[n * D_ + k] : Wc[(n - 512) * D_ + k];
            Wsc[j] = __float2bfloat16(v); continue;
        }
        j -= NWS;
        bsum[j] = b_ih[j] + b_hh[j];
    }
}

// -------- fold: Wfold = W_hh + Wy@Wd (bf16), bfold = bsum + Wy@bd ----------
__global__ void __launch_bounds__(256) k_fold(const float* __restrict__ W_ih,
                     const float* __restrict__ W_hh, const float* __restrict__ Wd,
                     const float* __restrict__ bd, const float* __restrict__ bsum,
                     bf16* __restrict__ Wfold, float* __restrict__ bfold)
{
    int gj0 = blockIdx.x * 16;
    int t = threadIdx.x;
    int gj = gj0 + (t >> 4);
    int c0 = (t & 15) * 32;
    float accv[32];
    {
        const float4* hh = (const float4*)(W_hh + (long)gj * H_ + c0);
        #pragma unroll
        for (int c4 = 0; c4 < 8; ++c4) {
            float4 w = hh[c4];
            accv[c4*4+0] = w.x; accv[c4*4+1] = w.y; accv[c4*4+2] = w.z; accv[c4*4+3] = w.w;
        }
    }
    for (int o = 0; o < O_; ++o) {
        float wy = W_ih[(long)gj * 320 + o];
        const float4* wdr = (const float4*)(Wd + (long)o * H_ + c0);
        #pragma unroll
        for (int c4 = 0; c4 < 8; ++c4) {
            float4 w = wdr[c4];
            accv[c4*4+0] = fmaf(wy, w.x, accv[c4*4+0]);
            accv[c4*4+1] = fmaf(wy, w.y, accv[c4*4+1]);
            accv[c4*4+2] = fmaf(wy, w.z, accv[c4*4+2]);
            accv[c4*4+3] = fmaf(wy, w.w, accv[c4*4+3]);
        }
    }
    #pragma unroll
    for (int c4 = 0; c4 < 8; ++c4) {
        bf16x8 v;
        #pragma unroll
        for (int i = 0; i < 4; ++i) v[i] = f2bs(accv[c4*4+i]);
        #pragma unroll
        for (int i = 4; i < 8; ++i) v[i] = 0;
        // write 4 bf16 at a time via scalar to keep it simple & correct
        short* wf = (short*)Wfold + (long)gj * H_ + c0 + c4 * 4;
        wf[0] = v[0]; wf[1] = v[1]; wf[2] = v[2]; wf[3] = v[3];
    }
    if (t < 16) {
        int g = gj0 + t;
        float bacc = bsum[g];
        for (int o = 0; o < O_; ++o)
            bacc = fmaf(W_ih[(long)g * 320 + o], bd[o], bacc);
        bfold[g] = bacc;
    }
}

// ------- init (MFMA): x_last(512x256) @ Wsc^T(1024x256) -> h0 | c0 ---------
__global__ void __launch_bounds__(256) k_init2(const bf16* __restrict__ x_bf,
                       const bf16* __restrict__ Wsc, const float* __restrict__ bs,
                       const float* __restrict__ bc, bf16* __restrict__ q_buf,
                       float* __restrict__ c_f32)
{
    int wave = threadIdx.x >> 6, lane = threadIdx.x & 63;
    int m0 = blockIdx.x * 16;
    int n0 = blockIdx.y * 64 + wave * 16;
    int r = lane & 15, ko = (lane >> 4) * 8, rj = (lane >> 4) * 4;
    const short* xp = (const short*)x_bf;
    const short* wp = (const short*)Wsc;
    f32x4 acc = {};
    #pragma unroll
    for (int k0 = 0; k0 < D_; k0 += 32) {
        bf16x8 a  = *(const bf16x8*)(xp + (long)(m0 + r) * (WIN_ * D_) + 127 * D_ + k0 + ko);
        bf16x8 bb = *(const bf16x8*)(wp + (long)(n0 + r) * D_ + k0 + ko);
        acc = __builtin_amdgcn_mfma_f32_16x16x32_bf16(a, bb, acc, 0, 0, 0);
    }
    int n = n0 + r;
    if (n0 < 512) {
        float bias = bs[n];
        #pragma unroll
        for (int j = 0; j < 4; ++j) {
            int b = m0 + rj + j;
            float hv = fast_tanh(acc[j] + bias);
            q_buf[(long)b * K2H + n] = __float2bfloat16(hv);
        }
    } else {
        float bias = bc[n - 512];
        #pragma unroll
        for (int j = 0; j < 4; ++j) {
            int b = m0 + rj + j;
            float cv = fast_sig(acc[j] + bias);
            q_buf[(long)b * K2H + n]        = __float2bfloat16(cv);
            c_f32[(long)b * H_ + (n - 512)] = cv;
        }
    }
}

// ---------------- Uk[b] = U @ x[b]^T  (x-tile staged in LDS) ----------------
__global__ void __launch_bounds__(256) k_uk(const bf16* __restrict__ U_bf,
                    const bf16* __restrict__ x_bf, bf16* __restrict__ Uk)
{
    __shared__ __align__(16) short xs[64][264];
    int b  = blockIdx.y;
    int v0 = (blockIdx.x >> 1) * 64;
    int w0 = (blockIdx.x & 1) * 64;
    {
        const short* xg = (const short*)x_bf + (long)b * (WIN_ * D_) + (long)w0 * D_;
        int row = threadIdx.x >> 2, cc = (threadIdx.x & 3) * 64;
        #pragma unroll
        for (int i = 0; i < 8; ++i)
            *(bf16x8*)(&xs[row][cc + i * 8]) = *(const bf16x8*)(xg + (long)row * D_ + cc + i * 8);
    }
    __syncthreads();
    int lane = threadIdx.x & 63;
    int wave = threadIdx.x >> 6;
    int r  = lane & 15;
    int ko = (lane >> 4) * 8;
    const short* Up = (const short*)U_bf + (long)(v0 + wave * 16 + r) * D_;
    f32x4 acc[4] = {};
    #pragma unroll 2
    for (int k0 = 0; k0 < D_; k0 += 32) {
        bf16x8 a = *(const bf16x8*)(Up + k0 + ko);
        #pragma unroll
        for (int f = 0; f < 4; ++f) {
            bf16x8 bb = *(const bf16x8*)(&xs[f * 16 + r][k0 + ko]);
            acc[f] = __builtin_amdgcn_mfma_f32_16x16x32_bf16(a, bb, acc[f], 0, 0, 0);
        }
    }
    bf16* up = Uk + (long)b * (D_ * WIN_);
    int vbase = v0 + wave * 16 + (lane >> 4) * 4;
    #pragma unroll
    for (int f = 0; f < 4; ++f) {
        int w = w0 + f * 16 + r;
        #pragma unroll
        for (int j = 0; j < 4; ++j)
            up[(long)(vbase + j) * WIN_ + w] = __float2bfloat16(acc[f][j]);
    }
}

// ---------------- k_mix: finish gates(s-1)+LSTM, then Wq/gpre/y ----------------
// 32 blocks x 1024 threads; block owns 16 batches for the whole step.
__global__ void __launch_bounds__(1024) k_mix(
    const bf16* __restrict__ ctx_buf, const bf16* __restrict__ Wctx,
    float* __restrict__ gpre, const bf16* __restrict__ Wg,
    const float* __restrict__ bg, bf16* __restrict__ q_buf,
    float* __restrict__ c_f32, const bf16* __restrict__ Wqy,
    const float* __restrict__ bd, float* __restrict__ Wq_out,
    float* __restrict__ out_y, int s)
{
    const int tid  = threadIdx.x;
    const int wave = tid >> 6, lane = tid & 63;
    const int r = lane & 15, ko = (lane >> 4) * 8, rj = (lane >> 4) * 4;
    const int bb0 = blockIdx.x * 16;
    const short* ctxp = (const short*)ctx_buf;
    const short* wctxp = (const short*)Wctx;
    const short* qp = (const short*)q_buf;
    const short* wqyp = (const short*)Wqy;

    if (s > 0) {
        // phase 1: gates(s-1) for hj-slice [wave*32,+32), all 4 gates, + LSTM
        #pragma unroll
        for (int t = 0; t < 2; ++t) {
            int hj_t = wave * 32 + t * 16;
            f32x4 acc0 = {}, acc1 = {}, acc2 = {}, acc3 = {};
            #pragma unroll 2
            for (int k0 = 0; k0 < D_; k0 += 32) {
                bf16x8 a = *(const bf16x8*)(ctxp + (long)(bb0 + r) * D_ + k0 + ko);
                bf16x8 b0 = *(const bf16x8*)(wctxp + (long)(0 * H_ + hj_t + r) * D_ + k0 + ko);
                bf16x8 b1 = *(const bf16x8*)(wctxp + (long)(1 * H_ + hj_t + r) * D_ + k0 + ko);
                bf16x8 b2 = *(const bf16x8*)(wctxp + (long)(2 * H_ + hj_t + r) * D_ + k0 + ko);
                bf16x8 b3 = *(const bf16x8*)(wctxp + (long)(3 * H_ + hj_t + r) * D_ + k0 + ko);
                acc0 = __builtin_amdgcn_mfma_f32_16x16x32_bf16(a, b0, acc0, 0, 0, 0);
                acc1 = __builtin_amdgcn_mfma_f32_16x16x32_bf16(a, b1, acc1, 0, 0, 0);
                acc2 = __builtin_amdgcn_mfma_f32_16x16x32_bf16(a, b2, acc2, 0, 0, 0);
                acc3 = __builtin_amdgcn_mfma_f32_16x16x32_bf16(a, b3, acc3, 0, 0, 0);
            }
            int hj = hj_t + r;
            #pragma unroll
            for (int j = 0; j < 4; ++j) {
                int b = bb0 + rj + j;
                const float* gp = gpre + (long)b * NG;
                float iv = acc0[j] + gp[hj];
                float fv = acc1[j] + gp[H_ + hj];
                float gv = acc2[j] + gp[2 * H_ + hj];
                float ov = acc3[j] + gp[3 * H_ + hj];
                float c_old = c_f32[(long)b * H_ + hj];
                float cn = fast_sig(fv) * c_old + fast_sig(iv) * fast_tanh(gv);
                float hn = fast_sig(ov) * fast_tanh(cn);
                c_f32[(long)b * H_ + hj] = cn;
                q_buf[(long)b * K2H + hj]      = __float2bfloat16(hn);
                q_buf[(long)b * K2H + H_ + hj] = __float2bfloat16(cn);
            }
        }
        __syncthreads();   // drain q_buf writes; same CU -> coherent re-read
    }

    if (s < P_) {
        // phase 2a: gpre(s) = h(s) @ Wg^T + bg   (wave -> 8 n-tiles of 2048)
        const short* wgp = (const short*)Wg;
        #pragma unroll
        for (int t = 0; t < 8; ++t) {
            int n0 = wave * 128 + t * 16;
            f32x4 acc = {};
            #pragma unroll 4
            for (int k0 = 0; k0 < H_; k0 += 32) {
                bf16x8 a  = *(const bf16x8*)(qp + (long)(bb0 + r) * K2H + k0 + ko);
                bf16x8 bb = *(const bf16x8*)(wgp + (long)(n0 + r) * H_ + k0 + ko);
                acc = __builtin_amdgcn_mfma_f32_16x16x32_bf16(a, bb, acc, 0, 0, 0);
            }
            int n = n0 + r;
            float bias = bg[n];
            #pragma unroll
            for (int j = 0; j < 4; ++j)
                gpre[(long)(bb0 + rj + j) * NG + n] = acc[j] + bias;
        }
        // phase 2b: Wq(s) = q(s) @ W^T  (wave -> 1 n-tile of 256)
        {
            int n0 = wave * 16;
            f32x4 acc = {};
            #pragma unroll 4
            for (int k0 = 0; k0 < K2H; k0 += 32) {
                bf16x8 a  = *(const bf16x8*)(qp + (long)(bb0 + r) * K2H + k0 + ko);
                bf16x8 bb = *(const bf16x8*)(wqyp + (long)(n0 + r) * K2H + k0 + ko);
                acc = __builtin_amdgcn_mfma_f32_16x16x32_bf16(a, bb, acc, 0, 0, 0);
            }
            int n = n0 + r;
            #pragma unroll
            for (int j = 0; j < 4; ++j)
                Wq_out[(long)(bb0 + rj + j) * D_ + n] = acc[j];
        }
    }

    if (s > 0 && wave < 4) {
        // y(s-1) = h(s) @ Wd^T + bd  (waves 0..3)
        int n0 = 256 + wave * 16;
        f32x4 acc = {};
        #pragma unroll 4
        for (int k0 = 0; k0 < H_; k0 += 32) {
            bf16x8 a  = *(const bf16x8*)(qp + (long)(bb0 + r) * K2H + k0 + ko);
            bf16x8 bb = *(const bf16x8*)(wqyp + (long)(n0 + r) * K2H + k0 + ko);
            acc = __builtin_amdgcn_mfma_f32_16x16x32_bf16(a, bb, acc, 0, 0, 0);
        }
        int o = wave * 16 + r;
        float bias = bd[o];
        #pragma unroll
        for (int j = 0; j < 4; ++j)
            out_y[((long)(bb0 + rj + j) * P_ + (s - 1)) * O_ + o] = acc[j] + bias;
    }
}

// ---------------- attention: 2 batches per 512-thread block ----------------
__global__ void __launch_bounds__(512) k_att(
    const bf16* __restrict__ x_bf, const bf16* __restrict__ Uk,
    const float* __restrict__ Wq, const float* __restrict__ V,
    bf16* __restrict__ ctx_buf, float* __restrict__ out_w, int s)
{
    __shared__ float v_s[D_];
    __shared__ float wq_s[2][D_];
    __shared__ float part[2][4][WIN_];
    __shared__ float att_s[2][WIN_];
    __shared__ float cpart[2][2][D_];
    __shared__ float redw[2][4];

    const int tid = threadIdx.x;
    const int b0  = blockIdx.x * 2;
    const int tb  = tid >> 8;
    const int t2  = tid & 255;

    if (tid < D_) v_s[tid] = V[tid];
    { int bb = tid >> 8, n = tid & 255; wq_s[bb][n] = Wq[(long)(b0 + bb) * D_ + n]; }
    __syncthreads();

    const int b = b0 + tb;
    {   // score partials: thread = (w-pair, v-quarter)
        int w2 = t2 & 63, vq = t2 >> 6;
        const unsigned int* ukp =
            (const unsigned int*)(Uk + (long)b * (D_ * WIN_) + (long)vq * 64 * WIN_) + w2;
        float sc0 = 0.f, sc1 = 0.f;
        #pragma unroll 8
        for (int i = 0; i < 64; ++i) {
            unsigned int u = ukp[(long)i * 64];
            int v = vq * 64 + i;
            float wqv = wq_s[tb][v], vv = v_s[v];
            sc0 += vv * fast_tanh(wqv + b_lo(u));
            sc1 += vv * fast_tanh(wqv + b_hi(u));
        }
        part[tb][vq][w2 * 2]     = sc0;
        part[tb][vq][w2 * 2 + 1] = sc1;
    }
    __syncthreads();
    float e = 0.f, scw = 0.f;
    if (t2 < WIN_) {
        scw = part[tb][0][t2] + part[tb][1][t2] + part[tb][2][t2] + part[tb][3][t2];
        float m = scw;
        #pragma unroll
        for (int off = 32; off > 0; off >>= 1) m = fmaxf(m, __shfl_xor(m, off));
        if ((tid & 63) == 0) redw[tb][t2 >> 6] = m;
    }
    __syncthreads();
    if (t2 < WIN_) {
        float m = fmaxf(redw[tb][0], redw[tb][1]);
        e = __expf(scw - m);
        float l = e;
        #pragma unroll
        for (int off = 32; off > 0; off >>= 1) l += __shfl_xor(l, off);
        if ((tid & 63) == 0) redw[tb][2 + (t2 >> 6)] = l;
    }
    __syncthreads();
    if (t2 < WIN_) {
        float l = redw[tb][2] + redw[tb][3];
        float a = __fdividef(e, l);
        att_s[tb][t2] = a;
        out_w[((long)b * P_ + s) * WIN_ + t2] = a;
    }
    __syncthreads();
    {   // ctx: thread = (d-pair, w-half)
        int d2 = t2 & 127, wh = t2 >> 7;
        const unsigned int* xp =
            (const unsigned int*)(x_bf + (long)b * (WIN_ * D_) + (long)wh * 64 * D_) + d2;
        float c0 = 0.f, c1 = 0.f;
        #pragma unroll 8
        for (int i = 0; i < 64; ++i) {
            unsigned int u = xp[(long)i * 128];
            float a = att_s[tb][wh * 64 + i];
            c0 += a * b_lo(u);
            c1 += a * b_hi(u);
        }
        cpart[tb][wh][d2 * 2]     = c0;
        cpart[tb][wh][d2 * 2 + 1] = c1;
    }
    __syncthreads();
    if (t2 < 128) {
        int d = t2 * 2;
        float f0 = cpart[tb][0][d] + cpart[tb][1][d];
        float f1 = cpart[tb][0][d + 1] + cpart[tb][1][d + 1];
        *(unsigned int*)(ctx_buf + (long)b * D_ + d) = pack2(f0, f1);
    }
}

// ---------------------------------------------------------------------------
extern "C" void kernel_launch(void* const* d_in, const int* in_sizes, int n_in,
                              void* d_out, int out_size, void* d_ws, size_t ws_size,
                              hipStream_t stream)
{
    const float* x    = (const float*)d_in[0];
    const float* V    = (const float*)d_in[1];
    const float* W    = (const float*)d_in[2];
    const float* U    = (const float*)d_in[3];
    const float* W_ih = (const float*)d_in[4];
    const float* W_hh = (const float*)d_in[5];
    const float* b_ih = (const float*)d_in[6];
    const float* b_hh = (const float*)d_in[7];
    const float* Wd   = (const float*)d_in[8];
    const float* bd   = (const float*)d_in[9];
    const float* Ws   = (const float*)d_in[10];
    const float* bs   = (const float*)d_in[11];
    const float* Wc   = (const float*)d_in[12];
    const float* bc   = (const float*)d_in[13];

    float* out_y = (float*)d_out;                         // (512,64,64)
    float* out_w = (float*)d_out + (long)B_ * P_ * O_;    // (512,64,128)

    char* p = (char*)d_ws;
    auto alloc = [&](size_t bytes) { char* r = p; p += (bytes + 255) & ~(size_t)255; return r; };
    bf16*  x_bf   = (bf16*) alloc((size_t)B_ * WIN_ * D_ * 2);   // 33.5 MB
    bf16*  Uk     = (bf16*) alloc((size_t)B_ * D_ * WIN_ * 2);   // 33.5 MB
    bf16*  q_buf  = (bf16*) alloc((size_t)B_ * K2H * 2);         // 1 MB
    bf16*  ctx_buf= (bf16*) alloc((size_t)B_ * D_ * 2);          // 256 KB
    float* gpre   = (float*)alloc((size_t)B_ * NG * 4);          // 4 MB
    float* Wq     = (float*)alloc((size_t)B_ * D_ * 4);          // 512 KB
    float* c_f32  = (float*)alloc((size_t)B_ * H_ * 4);          // 1 MB
    bf16*  Wqy    = (bf16*) alloc((size_t)NQY * K2H * 2);        // 640 KB
    bf16*  Wctx   = (bf16*) alloc((size_t)NG * D_ * 2);          // 1 MB
    bf16*  Whh_bf = (bf16*) alloc((size_t)NG * H_ * 2);          // 2 MB
    bf16*  Wfold  = (bf16*) alloc((size_t)NG * H_ * 2);          // 2 MB
    bf16*  U_bf   = (bf16*) alloc((size_t)D_ * D_ * 2);          // 128 KB
    bf16*  Wsc    = (bf16*) alloc((size_t)K2H * D_ * 2);         // 512 KB
    float* bsum   = (float*)alloc((size_t)NG * 4);               // 8 KB
    float* bfold  = (float*)alloc((size_t)NG * 4);               // 8 KB

    k_prep<<<4096, 256, 0, stream>>>(x, W, U, W_ih, W_hh, b_ih, b_hh, Wd, Ws, Wc,
                                     x_bf, Wqy, Wctx, Whh_bf, U_bf, Wsc, bsum);
    k_fold<<<128, 256, 0, stream>>>(W_ih, W_hh, Wd, bd, bsum, Wfold, bfold);
    k_init2<<<dim3(32, 16), 256, 0, stream>>>(x_bf, Wsc, bs, bc, q_buf, c_f32);
    k_uk<<<dim3(8, 512), 256, 0, stream>>>(U_bf, x_bf, Uk);

    for (int s = 0; s < P_; ++s) {
        k_mix<<<32, 1024, 0, stream>>>(ctx_buf, Wctx, gpre,
                                       (s == 0) ? Whh_bf : Wfold,
                                       (s == 0) ? bsum : bfold,
                                       q_buf, c_f32, Wqy, bd, Wq, out_y, s);
        k_att<<<256, 512, 0, stream>>>(x_bf, Uk, Wq, V, ctx_buf, out_w, s);
    }
    // tail: finish gates(63) -> h(64) -> y(63)
    k_mix<<<32, 1024, 0, stream>>>(ctx_buf, Wctx, gpre, Wfold, bfold,
                                   q_buf, c_f32, Wqy, bd, Wq, out_y, P_);
}

// Round 6
// 2508.688 us; speedup vs baseline: 5.1856x; 5.1856x over previous
//
#include <hip/hip_runtime.h>
#include <hip/hip_bf16.h>

// Problem dims
#define B_   512
#define WIN_ 128
#define D_   256
#define H_   512
#define O_   64
#define P_   64
#define K2H  1024   // 2H (q = [h|c])
#define KG   832    // gates GEMM K = O(64) + D(256) + H(512)
#define NG   2048   // 4*H gate dims
#define NSLN 320    // slab N: 256 (Wq) + 64 (y)

typedef __attribute__((ext_vector_type(8))) short bf16x8;
typedef __attribute__((ext_vector_type(4))) float f32x4;
using bf16 = __hip_bfloat16;

__device__ __forceinline__ float fast_tanh(float x){
    float e = __expf(2.f * x);
    return 1.f - __fdividef(2.f, e + 1.f);
}
__device__ __forceinline__ float fast_sig(float x){
    return __fdividef(1.f, 1.f + __expf(-x));
}
__device__ __forceinline__ float b_lo(unsigned int u){ return __uint_as_float(u << 16); }
__device__ __forceinline__ float b_hi(unsigned int u){ return __uint_as_float(u & 0xffff0000u); }
__device__ __forceinline__ short f2bs(float v){
    return (short)__builtin_bit_cast(unsigned short, __float2bfloat16(v));
}
__device__ __forceinline__ unsigned int pack2(float a, float b){
    unsigned short sa = __builtin_bit_cast(unsigned short, __float2bfloat16(a));
    unsigned short sb = __builtin_bit_cast(unsigned short, __float2bfloat16(b));
    return (unsigned int)sa | ((unsigned int)sb << 16);
}

// ---------------- prep: dtype conversions + weight packing ----------------
// Wsl[by][n][k] (8 x 320 x 128 bf16): K-slice 'by' of [W ; Wd] for slab partials.
//   n<256:  k<64 -> W[n][by*64+k]       ; k>=64 -> W[n][512+by*64+(k-64)]
//   n>=256: k<64 -> Wd[n-256][by*64+k]  ; k>=64 -> 0
__global__ void k_prep(const float* __restrict__ x, const float* __restrict__ W,
                       const float* __restrict__ U, const float* __restrict__ W_ih,
                       const float* __restrict__ W_hh, const float* __restrict__ b_ih,
                       const float* __restrict__ b_hh, const float* __restrict__ Wd,
                       const float* __restrict__ Ws, const float* __restrict__ Wc,
                       bf16* __restrict__ x_bf, bf16* __restrict__ Wcomb,
                       bf16* __restrict__ Wsl, bf16* __restrict__ U_bf,
                       bf16* __restrict__ Wsc, float* __restrict__ bsum)
{
    const long NXv = (long)B_ * WIN_ * D_ / 8;    // 2,097,152 (8 floats each)
    const long NWC = (long)NG * KG;               // 1,703,936
    const long NSL = (long)8 * NSLN * 128;        // 327,680
    const long NU  = (long)D_ * D_;               // 65,536
    const long NWS = (long)K2H * D_;              // 262,144
    const long NB  = NG;
    const long total = NXv + NWC + NSL + NU + NWS + NB;
    for (long i = (long)blockIdx.x * blockDim.x + threadIdx.x; i < total;
         i += (long)gridDim.x * blockDim.x) {
        long j = i;
        if (j < NXv) {
            const float4* xp = (const float4*)x + j * 2;
            float4 a = xp[0], b = xp[1];
            bf16x8 v;
            v[0] = f2bs(a.x); v[1] = f2bs(a.y); v[2] = f2bs(a.z); v[3] = f2bs(a.w);
            v[4] = f2bs(b.x); v[5] = f2bs(b.y); v[6] = f2bs(b.z); v[7] = f2bs(b.w);
            *(bf16x8*)((short*)x_bf + j * 8) = v;
            continue;
        }
        j -= NXv;
        if (j < NWC) {      // [W_ih | W_hh] packed K=832
            long n = j / KG, k = j % KG;
            float v = (k < 320) ? W_ih[n * 320 + k] : W_hh[n * 512 + (k - 320)];
            Wcomb[j] = __float2bfloat16(v); continue;
        }
        j -= NWC;
        if (j < NSL) {
            long by = j / (NSLN * 128);
            long rem = j % (NSLN * 128);
            long n = rem / 128, k = rem % 128;
            float v;
            if (n < 256) v = (k < 64) ? W[n * K2H + by * 64 + k]
                                      : W[n * K2H + 512 + by * 64 + (k - 64)];
            else         v = (k < 64) ? Wd[(n - 256) * H_ + by * 64 + k] : 0.f;
            Wsl[j] = __float2bfloat16(v); continue;
        }
        j -= NSL;
        if (j < NU) { U_bf[j] = __float2bfloat16(U[j]); continue; }
        j -= NU;
        if (j < NWS) {      // [Ws;Wc]
            long n = j / D_, k = j % D_;
            float v = (n < 512) ? Ws[n * D_ + k] : Wc[(n - 512) * D_ + k];
            Wsc[j] = __float2bfloat16(v); continue;
        }
        j -= NWS;
        bsum[j] = b_ih[j] + b_hh[j];
    }
}

// ------- init (MFMA): x_last(512x256) @ Wsc^T(1024x256) -> h0 | c0 ---------
__global__ void __launch_bounds__(256) k_init2(const bf16* __restrict__ x_bf,
                       const bf16* __restrict__ Wsc, const float* __restrict__ bs,
                       const float* __restrict__ bc, bf16* __restrict__ q_buf,
                       bf16* __restrict__ A0, float* __restrict__ c_f32)
{
    int wave = threadIdx.x >> 6, lane = threadIdx.x & 63;
    int m0 = blockIdx.x * 16;
    int n0 = blockIdx.y * 64 + wave * 16;
    int r = lane & 15, ko = (lane >> 4) * 8, rj = (lane >> 4) * 4;
    const short* xp = (const short*)x_bf;
    const short* wp = (const short*)Wsc;
    f32x4 acc = {};
    #pragma unroll
    for (int k0 = 0; k0 < D_; k0 += 32) {
        bf16x8 a  = *(const bf16x8*)(xp + (long)(m0 + r) * (WIN_ * D_) + 127 * D_ + k0 + ko);
        bf16x8 bb = *(const bf16x8*)(wp + (long)(n0 + r) * D_ + k0 + ko);
        acc = __builtin_amdgcn_mfma_f32_16x16x32_bf16(a, bb, acc, 0, 0, 0);
    }
    int n = n0 + r;
    if (n0 < 512) {          // h0
        float bias = bs[n];
        #pragma unroll
        for (int j = 0; j < 4; ++j) {
            int b = m0 + rj + j;
            float hv = fast_tanh(acc[j] + bias);
            bf16 hb = __float2bfloat16(hv);
            q_buf[(long)b * K2H + n]   = hb;
            A0[(long)b * KG + 320 + n] = hb;
        }
    } else {                 // c0
        float bias = bc[n - 512];
        #pragma unroll
        for (int j = 0; j < 4; ++j) {
            int b = m0 + rj + j;
            float cv = fast_sig(acc[j] + bias);
            q_buf[(long)b * K2H + n]        = __float2bfloat16(cv);
            c_f32[(long)b * H_ + (n - 512)] = cv;
        }
    }
}

// ---------------- Uk[b] = U @ x[b]^T  (x-tile staged in LDS) ----------------
__global__ void __launch_bounds__(256) k_uk(const bf16* __restrict__ U_bf,
                    const bf16* __restrict__ x_bf, bf16* __restrict__ Uk)
{
    __shared__ __align__(16) short xs[64][264];
    int b  = blockIdx.y;
    int v0 = (blockIdx.x >> 1) * 64;
    int w0 = (blockIdx.x & 1) * 64;
    {
        const short* xg = (const short*)x_bf + (long)b * (WIN_ * D_) + (long)w0 * D_;
        int row = threadIdx.x >> 2, cc = (threadIdx.x & 3) * 64;
        #pragma unroll
        for (int i = 0; i < 8; ++i)
            *(bf16x8*)(&xs[row][cc + i * 8]) = *(const bf16x8*)(xg + (long)row * D_ + cc + i * 8);
    }
    __syncthreads();
    int lane = threadIdx.x & 63;
    int wave = threadIdx.x >> 6;
    int r  = lane & 15;
    int ko = (lane >> 4) * 8;
    const short* Up = (const short*)U_bf + (long)(v0 + wave * 16 + r) * D_;
    f32x4 acc[4] = {};
    #pragma unroll 2
    for (int k0 = 0; k0 < D_; k0 += 32) {
        bf16x8 a = *(const bf16x8*)(Up + k0 + ko);
        #pragma unroll
        for (int f = 0; f < 4; ++f) {
            bf16x8 bb = *(const bf16x8*)(&xs[f * 16 + r][k0 + ko]);
            acc[f] = __builtin_amdgcn_mfma_f32_16x16x32_bf16(a, bb, acc[f], 0, 0, 0);
        }
    }
    bf16* up = Uk + (long)b * (D_ * WIN_);
    int vbase = v0 + wave * 16 + (lane >> 4) * 4;
    #pragma unroll
    for (int f = 0; f < 4; ++f) {
        int w = w0 + f * 16 + r;
        #pragma unroll
        for (int j = 0; j < 4; ++j)
            up[(long)(vbase + j) * WIN_ + w] = __float2bfloat16(acc[f][j]);
    }
}

// ------- slab(0) from q_buf: slab[by][b][n] = [h|c]_by-slice @ Wsl[by]^T -------
__global__ void __launch_bounds__(256) k_slab0(const bf16* __restrict__ q_buf,
                     const bf16* __restrict__ Wsl, float* __restrict__ slab)
{
    int bx = blockIdx.x, by = blockIdx.y;
    int wave = threadIdx.x >> 6, lane = threadIdx.x & 63;
    int r = lane & 15, ko = (lane >> 4) * 8, rj = (lane >> 4) * 4;
    int m0 = bx * 16;
    const short* qp = (const short*)q_buf;
    const short* wp = (const short*)Wsl + (long)by * NSLN * 128;
    #pragma unroll
    for (int i = 0; i < 5; ++i) {
        int n0 = (wave * 5 + i) * 16;
        f32x4 acc = {};
        #pragma unroll
        for (int k0 = 0; k0 < 128; k0 += 32) {
            long koff = (k0 < 64) ? (by * 64 + k0) : (512 + by * 64 + (k0 - 64));
            bf16x8 a  = *(const bf16x8*)(qp + (long)(m0 + r) * K2H + koff + ko);
            bf16x8 bb = *(const bf16x8*)(wp + (long)(n0 + r) * 128 + k0 + ko);
            acc = __builtin_amdgcn_mfma_f32_16x16x32_bf16(a, bb, acc, 0, 0, 0);
        }
        int n = n0 + r;
        #pragma unroll
        for (int j = 0; j < 4; ++j)
            slab[((long)by * B_ + m0 + rj + j) * NSLN + n] = acc[j];
    }
}

// ---------------- attention: slab-reduce -> Wq,y ; score/softmax/ctx ----------
// 512 blocks x 256 threads, 1 batch per block
__global__ void __launch_bounds__(256) k_att(
    const bf16* __restrict__ x_bf, const bf16* __restrict__ Uk,
    const float* __restrict__ slab, const float* __restrict__ V,
    const float* __restrict__ bd, bf16* __restrict__ A_cur,
    float* __restrict__ out_y, float* __restrict__ out_w, int s)
{
    __shared__ float v_s[D_];
    __shared__ float wq_s[D_];
    __shared__ float part[4][WIN_];
    __shared__ float att_s[WIN_];
    __shared__ float cpart[2][D_];
    __shared__ float redw[4];

    const int b = blockIdx.x;
    const int t = threadIdx.x;

    v_s[t] = V[t];
    {   // Wq[b][t] = sum_by slab[by][b][t]
        float wsum = 0.f;
        #pragma unroll
        for (int by = 0; by < 8; ++by)
            wsum += slab[((long)by * B_ + b) * NSLN + t];
        wq_s[t] = wsum;
    }
    if (t < O_) {   // y(s-1)[b][t]
        float yv = bd[t];
        #pragma unroll
        for (int by = 0; by < 8; ++by)
            yv += slab[((long)by * B_ + b) * NSLN + 256 + t];
        if (s > 0) {
            out_y[((long)b * P_ + (s - 1)) * O_ + t] = yv;
            A_cur[(long)b * KG + t] = __float2bfloat16(yv);
        } else {
            A_cur[(long)b * KG + t] = __float2bfloat16(0.f);
        }
    }
    __syncthreads();

    {   // score partials: thread = (w-pair, v-quarter)
        int w2 = t & 63, vq = t >> 6;
        const unsigned int* ukp =
            (const unsigned int*)(Uk + (long)b * (D_ * WIN_) + (long)vq * 64 * WIN_) + w2;
        float sc0 = 0.f, sc1 = 0.f;
        #pragma unroll 8
        for (int i = 0; i < 64; ++i) {
            unsigned int u = ukp[(long)i * 64];
            int v = vq * 64 + i;
            float wqv = wq_s[v], vv = v_s[v];
            sc0 += vv * fast_tanh(wqv + b_lo(u));
            sc1 += vv * fast_tanh(wqv + b_hi(u));
        }
        part[vq][w2 * 2]     = sc0;
        part[vq][w2 * 2 + 1] = sc1;
    }
    __syncthreads();
    float e = 0.f, scw = 0.f;
    if (t < WIN_) {
        scw = part[0][t] + part[1][t] + part[2][t] + part[3][t];
        float m = scw;
        #pragma unroll
        for (int off = 32; off > 0; off >>= 1) m = fmaxf(m, __shfl_xor(m, off));
        if ((t & 63) == 0) redw[t >> 6] = m;
    }
    __syncthreads();
    if (t < WIN_) {
        float m = fmaxf(redw[0], redw[1]);
        e = __expf(scw - m);
        float l = e;
        #pragma unroll
        for (int off = 32; off > 0; off >>= 1) l += __shfl_xor(l, off);
        if ((t & 63) == 0) redw[2 + (t >> 6)] = l;
    }
    __syncthreads();
    if (t < WIN_) {
        float a = __fdividef(e, redw[2] + redw[3]);
        att_s[t] = a;
        out_w[((long)b * P_ + s) * WIN_ + t] = a;
    }
    __syncthreads();
    {   // ctx: thread = (d-pair, w-half)
        int d2 = t & 127, wh = t >> 7;
        const unsigned int* xp =
            (const unsigned int*)(x_bf + (long)b * (WIN_ * D_) + (long)wh * 64 * D_) + d2;
        float c0 = 0.f, c1 = 0.f;
        #pragma unroll 8
        for (int i = 0; i < 64; ++i) {
            unsigned int u = xp[(long)i * 128];
            float a = att_s[wh * 64 + i];
            c0 += a * b_lo(u);
            c1 += a * b_hi(u);
        }
        cpart[wh][d2 * 2]     = c0;
        cpart[wh][d2 * 2 + 1] = c1;
    }
    __syncthreads();
    if (t < 128) {
        int d = t * 2;
        float f0 = cpart[0][d] + cpart[1][d];
        float f1 = cpart[0][d + 1] + cpart[1][d + 1];
        *(unsigned int*)(A_cur + (long)b * KG + O_ + d) = pack2(f0, f1);
    }
}

// ------- gates GEMM + LSTM + slab partials (Wq/y lookahead) -------
// grid (32, 8) x 256 thr: bx = 16-batch tile, by = 64-j slice (x4 gates)
__global__ void __launch_bounds__(256) k_gates(const bf16* __restrict__ A_in,
                     const bf16* __restrict__ Wcomb, const bf16* __restrict__ Wsl,
                     const float* __restrict__ bsum, float* __restrict__ c_f32,
                     bf16* __restrict__ A_out, float* __restrict__ slab)
{
    __shared__ short lhc[16][136];   // [batch][64 h | 64 c], +8 pad
    int bx = blockIdx.x, by = blockIdx.y;
    int wave = threadIdx.x >> 6, lane = threadIdx.x & 63;
    int r = lane & 15, ko = (lane >> 4) * 8, rj = (lane >> 4) * 4;
    int m0 = bx * 16;
    int jw = by * 64 + wave * 16;
    const short* ap = (const short*)A_in;
    const short* wp = (const short*)Wcomb;
    f32x4 acc[4] = {};
    long arow = (long)(m0 + r) * KG;
    #pragma unroll 2
    for (int k0 = 0; k0 < KG; k0 += 32) {
        bf16x8 a = *(const bf16x8*)(ap + arow + k0 + ko);
        #pragma unroll
        for (int g = 0; g < 4; ++g) {
            bf16x8 bb = *(const bf16x8*)(wp + (long)(g * H_ + jw + r) * KG + k0 + ko);
            acc[g] = __builtin_amdgcn_mfma_f32_16x16x32_bf16(a, bb, acc[g], 0, 0, 0);
        }
    }
    int jj = jw + r;
    float bi = bsum[jj], bf_ = bsum[H_ + jj], bg = bsum[2*H_ + jj], bo = bsum[3*H_ + jj];
    #pragma unroll
    for (int j = 0; j < 4; ++j) {
        int b = m0 + rj + j;
        float iv = acc[0][j] + bi;
        float fv = acc[1][j] + bf_;
        float gv = acc[2][j] + bg;
        float ov = acc[3][j] + bo;
        float c_old = c_f32[(long)b * H_ + jj];
        float cn = fast_sig(fv) * c_old + fast_sig(iv) * fast_tanh(gv);
        float hn = fast_sig(ov) * fast_tanh(cn);
        c_f32[(long)b * H_ + jj] = cn;
        short hb = f2bs(hn);
        A_out[(long)b * KG + 320 + jj] = __builtin_bit_cast(bf16, (unsigned short)hb);
        lhc[rj + j][wave * 16 + r]      = hb;
        lhc[rj + j][64 + wave * 16 + r] = f2bs(cn);
    }
    __syncthreads();
    // slab partial: P(16x320) = lhc(16x128) @ Wsl[by]^T
    const short* wsl = (const short*)Wsl + (long)by * NSLN * 128;
    #pragma unroll
    for (int i = 0; i < 5; ++i) {
        int n0 = (wave * 5 + i) * 16;
        f32x4 pac = {};
        #pragma unroll
        for (int k0 = 0; k0 < 128; k0 += 32) {
            bf16x8 a  = *(const bf16x8*)(&lhc[r][k0 + ko]);
            bf16x8 bb = *(const bf16x8*)(wsl + (long)(n0 + r) * 128 + k0 + ko);
            pac = __builtin_amdgcn_mfma_f32_16x16x32_bf16(a, bb, pac, 0, 0, 0);
        }
        int n = n0 + r;
        #pragma unroll
        for (int j = 0; j < 4; ++j)
            slab[((long)by * B_ + m0 + rj + j) * NSLN + n] = pac[j];
    }
}

// ---------------- final y (step 63) from slab(64) ----------------
__global__ void __launch_bounds__(256) k_yfin(const float* __restrict__ slab,
                     const float* __restrict__ bd, float* __restrict__ out_y)
{
    int b = blockIdx.x * 4 + (threadIdx.x >> 6);
    int o = threadIdx.x & 63;
    float yv = bd[o];
    #pragma unroll
    for (int by = 0; by < 8; ++by)
        yv += slab[((long)by * B_ + b) * NSLN + 256 + o];
    out_y[((long)b * P_ + 63) * O_ + o] = yv;
}

// ---------------------------------------------------------------------------
extern "C" void kernel_launch(void* const* d_in, const int* in_sizes, int n_in,
                              void* d_out, int out_size, void* d_ws, size_t ws_size,
                              hipStream_t stream)
{
    const float* x    = (const float*)d_in[0];
    const float* V    = (const float*)d_in[1];
    const float* W    = (const float*)d_in[2];
    const float* U    = (const float*)d_in[3];
    const float* W_ih = (const float*)d_in[4];
    const float* W_hh = (const float*)d_in[5];
    const float* b_ih = (const float*)d_in[6];
    const float* b_hh = (const float*)d_in[7];
    const float* Wd   = (const float*)d_in[8];
    const float* bd   = (const float*)d_in[9];
    const float* Ws   = (const float*)d_in[10];
    const float* bs   = (const float*)d_in[11];
    const float* Wc   = (const float*)d_in[12];
    const float* bc   = (const float*)d_in[13];

    float* out_y = (float*)d_out;                         // (512,64,64)
    float* out_w = (float*)d_out + (long)B_ * P_ * O_;    // (512,64,128)

    char* p = (char*)d_ws;
    auto alloc = [&](size_t bytes) { char* r = p; p += (bytes + 255) & ~(size_t)255; return r; };
    bf16*  x_bf  = (bf16*) alloc((size_t)B_ * WIN_ * D_ * 2);   // 33.5 MB
    bf16*  Uk    = (bf16*) alloc((size_t)B_ * D_ * WIN_ * 2);   // 33.5 MB
    bf16*  q_buf = (bf16*) alloc((size_t)B_ * K2H * 2);         // 1 MB
    bf16*  A0    = (bf16*) alloc((size_t)B_ * KG * 2);          // 852 KB
    bf16*  A1    = (bf16*) alloc((size_t)B_ * KG * 2);          // 852 KB
    float* c_f32 = (float*)alloc((size_t)B_ * H_ * 4);          // 1 MB
    float* slab  = (float*)alloc((size_t)8 * B_ * NSLN * 4);    // 5.24 MB
    bf16*  Wcomb = (bf16*) alloc((size_t)NG * KG * 2);          // 3.3 MB
    bf16*  Wsl   = (bf16*) alloc((size_t)8 * NSLN * 128 * 2);   // 655 KB
    bf16*  U_bf  = (bf16*) alloc((size_t)D_ * D_ * 2);          // 128 KB
    bf16*  Wsc   = (bf16*) alloc((size_t)K2H * D_ * 2);         // 512 KB
    float* bsum  = (float*)alloc((size_t)NG * 4);               // 8 KB
    bf16*  Abuf[2] = { A0, A1 };

    k_prep<<<4096, 256, 0, stream>>>(x, W, U, W_ih, W_hh, b_ih, b_hh, Wd, Ws, Wc,
                                     x_bf, Wcomb, Wsl, U_bf, Wsc, bsum);
    k_init2<<<dim3(32, 16), 256, 0, stream>>>(x_bf, Wsc, bs, bc, q_buf, A0, c_f32);
    k_uk<<<dim3(8, 512), 256, 0, stream>>>(U_bf, x_bf, Uk);
    k_slab0<<<dim3(32, 8), 256, 0, stream>>>(q_buf, Wsl, slab);

    for (int s = 0; s < P_; ++s) {
        k_att<<<512, 256, 0, stream>>>(x_bf, Uk, slab, V, bd,
                                       Abuf[s & 1], out_y, out_w, s);
        k_gates<<<dim3(32, 8), 256, 0, stream>>>(Abuf[s & 1], Wcomb, Wsl, bsum,
                                                 c_f32, Abuf[(s + 1) & 1], slab);
    }
    k_yfin<<<128, 256, 0, stream>>>(slab, bd, out_y);
}